// Round 1
// baseline (295.833 us; speedup 1.0000x reference)
//
#include <hip/hip_runtime.h>
#include <math.h>

#define DIN 128
#define DH  32
#define H1  8
#define H2  2
#define GNUM 64
#define DOUT 10
#define NEG_SLOPE 0.2f
#define SCAN_B 512

typedef __attribute__((ext_vector_type(8))) short sv8;
typedef __attribute__((ext_vector_type(4))) short sv4;
typedef __attribute__((ext_vector_type(4))) float fv4;

static __device__ __forceinline__ unsigned short f2bf(float f) {
    unsigned int u = __float_as_uint(f);
    unsigned int r = (u + 0x7fffu + ((u >> 16) & 1u)) >> 16;
    return (unsigned short)r;
}
static __device__ __forceinline__ float bf2f(unsigned short h) {
    return __uint_as_float(((unsigned int)h) << 16);
}

// ---------------------------------------------------------------------------
// Prep: zero deg, split x -> bf16 hi|lo rows [N,256], transpose+split W1/W2
// ---------------------------------------------------------------------------
__global__ void k_prep(const float* __restrict__ x,
                       const float* __restrict__ W1l, const float* __restrict__ W1r,
                       const float* __restrict__ W2l, const float* __restrict__ W2r,
                       unsigned short* __restrict__ xg,
                       short* __restrict__ B1th, short* __restrict__ B1tl,
                       short* __restrict__ B2th, short* __restrict__ B2tl,
                       int* __restrict__ zbase, int nz, int n) {
    int id = blockIdx.x * blockDim.x + threadIdx.x;
    if (id < nz) zbase[id] = 0;        // deg[N+1]
    const int NX = n * 32;             // 32 threads per row of x
    const int T1 = 512 * 128;
    const int T2 = 128 * 256;
    if (id < NX) {
        int m = id >> 5, j = id & 31;
        float4 v = *(const float4*)(x + (size_t)m * 128 + j * 4);
        unsigned short hx = f2bf(v.x), hy = f2bf(v.y), hz = f2bf(v.z), hw = f2bf(v.w);
        ushort4 hi; hi.x = hx; hi.y = hy; hi.z = hz; hi.w = hw;
        ushort4 lo;
        lo.x = f2bf(v.x - bf2f(hx)); lo.y = f2bf(v.y - bf2f(hy));
        lo.z = f2bf(v.z - bf2f(hz)); lo.w = f2bf(v.w - bf2f(hw));
        *(ushort4*)(xg + (size_t)m * 256 + j * 4) = hi;
        *(ushort4*)(xg + (size_t)m * 256 + 128 + j * 4) = lo;
    } else if (id < NX + T1) {
        int id1 = id - NX;
        int nn = id1 / 128, k = id1 - nn * 128;
        float v = (nn < 256) ? W1l[(size_t)k * 256 + nn] : W1r[(size_t)k * 256 + (nn - 256)];
        unsigned short h = f2bf(v);
        B1th[id1] = (short)h;
        B1tl[id1] = (short)f2bf(v - bf2f(h));
    } else if (id < NX + T1 + T2) {
        int id2 = id - NX - T1;
        int nn = id2 / 256, k = id2 - nn * 256;
        float v = (nn < 64) ? W2l[(size_t)k * 64 + nn] : W2r[(size_t)k * 64 + (nn - 64)];
        unsigned short h = f2bf(v);
        B2th[id2] = (short)h;
        B2tl[id2] = (short)f2bf(v - bf2f(h));
    }
}

// ---------------------------------------------------------------------------
// CSR build
// ---------------------------------------------------------------------------
__global__ void k_deg(const int* __restrict__ dst, int* __restrict__ deg, int E, int n) {
    int i = blockIdx.x * blockDim.x + threadIdx.x;
    if (i < E) {
        atomicAdd(&deg[dst[i]], 1);
    } else if (i < E + n) {
        atomicAdd(&deg[i - E], 1);   // self loop
    }
}

__global__ __launch_bounds__(SCAN_B)
void k_scan_partial(const int* __restrict__ deg, int* __restrict__ bsum, int n) {
    int i = blockIdx.x * SCAN_B + threadIdx.x;
    int v = (i < n) ? deg[i] : 0;
    #pragma unroll
    for (int m = 32; m >= 1; m >>= 1) v += __shfl_xor(v, m);
    __shared__ int red[SCAN_B / 64];
    if ((threadIdx.x & 63) == 0) red[threadIdx.x >> 6] = v;
    __syncthreads();
    if (threadIdx.x == 0) {
        int s = 0;
        #pragma unroll
        for (int k = 0; k < SCAN_B / 64; ++k) s += red[k];
        bsum[blockIdx.x] = s;
    }
}

__global__ __launch_bounds__(SCAN_B)
void k_scan_apply(int* __restrict__ deg, int* __restrict__ cursor,
                  const int* __restrict__ bsum, int n, int nb) {
    __shared__ int buf[SCAN_B];
    __shared__ int pfx_s, tot_s;
    const int t = threadIdx.x, b = blockIdx.x;
    if (t < 64) {
        int v = (t < nb) ? bsum[t] : 0;
        int incl = v;
        #pragma unroll
        for (int o = 1; o < 64; o <<= 1) {
            int w = __shfl_up(incl, o);
            if (t >= o) incl += w;
        }
        int pfx = (b == 0) ? 0 : __shfl(incl, b - 1);
        int tot = __shfl(incl, nb - 1);
        if (t == 0) { pfx_s = pfx; tot_s = tot; }
    }
    int i = b * SCAN_B + t;
    int v = (i < n) ? deg[i] : 0;
    buf[t] = v;
    __syncthreads();
    for (int o = 1; o < SCAN_B; o <<= 1) {
        int a = (t >= o) ? buf[t - o] : 0;
        __syncthreads();
        buf[t] += a;
        __syncthreads();
    }
    int excl = buf[t] - v + pfx_s;
    if (i < n) { deg[i] = excl; cursor[i] = excl; }
    if (b == 0 && t == 0) deg[n] = tot_s;
}

__global__ void k_scatter(const int* __restrict__ src, const int* __restrict__ dst,
                          int* __restrict__ cursor, int* __restrict__ csr_src, int E, int n) {
    int i = blockIdx.x * blockDim.x + threadIdx.x;
    if (i < E) {
        int d = dst[i];
        int pos = atomicAdd(&cursor[d], 1);
        csr_src[pos] = src[i];
    } else if (i < E + n) {
        int v = i - E;
        int pos = atomicAdd(&cursor[v], 1);
        csr_src[pos] = v;   // self loop
    }
}

// ---------------------------------------------------------------------------
// Layer-1 GEMM: no-LDS main loop. A = xg [M,256] bf16 (hi128|lo128 per row),
// fragments loaded directly from global (L2-resident), zero K-loop barriers.
// 3 products: Ah*Bh + Ah*Bl + Al*Bh. LDS only for the (unchanged) epilogue.
// ---------------------------------------------------------------------------
__global__ __launch_bounds__(256, 2)
void k_gemm1(const unsigned short* __restrict__ Ag,
             const short* __restrict__ Bth, const short* __restrict__ Btl,
             unsigned short* __restrict__ C,
             int M, int Ntot) {
    __shared__ float smc[64 * 68];
    const int tid = threadIdx.x;
    const int lane = tid & 63;
    const int wid = tid >> 6;
    const int wm = wid & 1, wn = wid >> 1;
    const int m0 = blockIdx.x * 128;
    const int n0 = blockIdx.y * 128;
    const int l15 = lane & 15, q = lane >> 4;

    fv4 acc[4][4] = {};

    const unsigned short* arow[4];
    #pragma unroll
    for (int fm = 0; fm < 4; ++fm) {
        int mg = m0 + wm * 64 + fm * 16 + l15;
        if (mg >= M) mg = M - 1;               // clamp; OOB rows never stored
        arow[fm] = Ag + (size_t)mg * 256;
    }
    const short* browh[4];
    const short* browl[4];
    #pragma unroll
    for (int fn = 0; fn < 4; ++fn) {
        int ng = n0 + wn * 64 + fn * 16 + l15;
        browh[fn] = Bth + (size_t)ng * 128;
        browl[fn] = Btl + (size_t)ng * 128;
    }

    #pragma unroll
    for (int c = 0; c < 4; ++c) {
        const int ko = c * 32 + q * 8;
        sv8 ah[4], al[4], bh[4], bl[4];
        #pragma unroll
        for (int fn = 0; fn < 4; ++fn) {
            bh[fn] = *(const sv8*)(browh[fn] + ko);
            bl[fn] = *(const sv8*)(browl[fn] + ko);
        }
        #pragma unroll
        for (int fm = 0; fm < 4; ++fm) {
            ah[fm] = *(const sv8*)(arow[fm] + ko);
            al[fm] = *(const sv8*)(arow[fm] + 128 + ko);
        }
        #pragma unroll
        for (int fm = 0; fm < 4; ++fm) {
            #pragma unroll
            for (int fn = 0; fn < 4; ++fn) {
                acc[fm][fn] = __builtin_amdgcn_mfma_f32_16x16x32_bf16(ah[fm], bh[fn], acc[fm][fn], 0, 0, 0);
                acc[fm][fn] = __builtin_amdgcn_mfma_f32_16x16x32_bf16(ah[fm], bl[fn], acc[fm][fn], 0, 0, 0);
                acc[fm][fn] = __builtin_amdgcn_mfma_f32_16x16x32_bf16(al[fm], bh[fn], acc[fm][fn], 0, 0, 0);
            }
        }
    }

    // epilogue: 4 slices (row-half s x col-half cn), 64x64 each, bf16 only
    #pragma unroll
    for (int s = 0; s < 2; ++s) {
        #pragma unroll
        for (int cn = 0; cn < 2; ++cn) {
            __syncthreads();
            if (wm == s && wn == cn) {
                #pragma unroll
                for (int fm = 0; fm < 4; ++fm)
                    #pragma unroll
                    for (int fn = 0; fn < 4; ++fn)
                        #pragma unroll
                        for (int r = 0; r < 4; ++r)
                            smc[(fm * 16 + q * 4 + r) * 68 + fn * 16 + l15] = acc[fm][fn][r];
            }
            __syncthreads();
            int lr = tid >> 2;              // 0..63
            int grow = m0 + s * 64 + lr;
            if (grow < M) {
                #pragma unroll
                for (int k4 = 0; k4 < 4; ++k4) {
                    int jj = (tid & 3) + k4 * 4;    // 0..15 float4 index
                    float4 vv = *(float4*)&smc[lr * 68 + jj * 4];
                    int gcol = n0 + cn * 64 + jj * 4;
                    ushort4 uu;
                    uu.x = f2bf(vv.x); uu.y = f2bf(vv.y);
                    uu.z = f2bf(vv.z); uu.w = f2bf(vv.w);
                    *(ushort4*)(C + (size_t)grow * Ntot + gcol) = uu;
                }
            }
        }
    }
}

// ---------------------------------------------------------------------------
// Layer-2 GEMM: no-LDS main loop, A = h1b [M,256] bf16 direct from global.
// Tile 128x64 (grid.y = 2 -> 470 blocks, vs 235 before). 2 products.
// ---------------------------------------------------------------------------
__global__ __launch_bounds__(256, 2)
void k_gemm_bf(const unsigned short* __restrict__ A, const short* __restrict__ Bth,
               const short* __restrict__ Btl,
               unsigned short* __restrict__ C,
               int M, int Ntot) {
    __shared__ float smc[64 * 36];
    const int tid = threadIdx.x;
    const int lane = tid & 63;
    const int wid = tid >> 6;
    const int wm = wid & 1, wn = wid >> 1;   // wn in {0,1}: 32-col halves
    const int m0 = blockIdx.x * 128;
    const int n0 = blockIdx.y * 64;
    const int l15 = lane & 15, q = lane >> 4;

    fv4 acc[4][2] = {};

    const unsigned short* arow[4];
    #pragma unroll
    for (int fm = 0; fm < 4; ++fm) {
        int mg = m0 + wm * 64 + fm * 16 + l15;
        if (mg >= M) mg = M - 1;
        arow[fm] = A + (size_t)mg * 256;
    }
    const short* browh[2];
    const short* browl[2];
    #pragma unroll
    for (int fn = 0; fn < 2; ++fn) {
        int ng = n0 + wn * 32 + fn * 16 + l15;
        browh[fn] = Bth + (size_t)ng * 256;
        browl[fn] = Btl + (size_t)ng * 256;
    }

    #pragma unroll 4
    for (int c = 0; c < 8; ++c) {
        const int ko = c * 32 + q * 8;
        sv8 ah[4], bh[2], bl[2];
        #pragma unroll
        for (int fn = 0; fn < 2; ++fn) {
            bh[fn] = *(const sv8*)(browh[fn] + ko);
            bl[fn] = *(const sv8*)(browl[fn] + ko);
        }
        #pragma unroll
        for (int fm = 0; fm < 4; ++fm)
            ah[fm] = *(const sv8*)(arow[fm] + ko);
        #pragma unroll
        for (int fm = 0; fm < 4; ++fm) {
            #pragma unroll
            for (int fn = 0; fn < 2; ++fn) {
                acc[fm][fn] = __builtin_amdgcn_mfma_f32_16x16x32_bf16(ah[fm], bh[fn], acc[fm][fn], 0, 0, 0);
                acc[fm][fn] = __builtin_amdgcn_mfma_f32_16x16x32_bf16(ah[fm], bl[fn], acc[fm][fn], 0, 0, 0);
            }
        }
    }

    // epilogue: 4 slices (row-half s x col-half cn), 64x32 each
    #pragma unroll
    for (int s = 0; s < 2; ++s) {
        #pragma unroll
        for (int cn = 0; cn < 2; ++cn) {
            __syncthreads();
            if (wm == s && wn == cn) {
                #pragma unroll
                for (int fm = 0; fm < 4; ++fm)
                    #pragma unroll
                    for (int fn = 0; fn < 2; ++fn)
                        #pragma unroll
                        for (int r = 0; r < 4; ++r)
                            smc[(fm * 16 + q * 4 + r) * 36 + fn * 16 + l15] = acc[fm][fn][r];
            }
            __syncthreads();
            int lr = tid >> 2;              // 0..63
            int grow = m0 + s * 64 + lr;
            if (grow < M) {
                #pragma unroll
                for (int k4 = 0; k4 < 2; ++k4) {
                    int jj = (tid & 3) + k4 * 4;    // 0..7 float4 index
                    float4 vv = *(float4*)&smc[lr * 36 + jj * 4];
                    int gcol = n0 + cn * 32 + jj * 4;
                    ushort4 uu;
                    uu.x = f2bf(vv.x); uu.y = f2bf(vv.y);
                    uu.z = f2bf(vv.z); uu.w = f2bf(vv.w);
                    *(ushort4*)(C + (size_t)grow * Ntot + gcol) = uu;
                }
            }
        }
    }
}

// ---------------------------------------------------------------------------
// Layer-1 edge pass: one wave per block. XLR[N,512] bf16: cols 0..255 = xl,
// 256..511 = xr. lane li (0..31) owns 8 ch; half = edge slot.
// ---------------------------------------------------------------------------
__global__ __launch_bounds__(64)
void k_edge1(const unsigned short* __restrict__ XLR,
             const int* __restrict__ offs, const int* __restrict__ csr,
             const float* __restrict__ att, const float* __restrict__ bias,
             unsigned short* __restrict__ out, int n) {
    const int lane = threadIdx.x;
    const int v = blockIdx.x;
    const int li = lane & 31;
    const int half = lane >> 5;
    const uint4* XL4 = (const uint4*)XLR;   // row = 64 uint4 (512 bf16)
    float av[8], xr[8];
    #pragma unroll
    for (int k = 0; k < 8; ++k) av[k] = att[li * 8 + k];
    {
        uint4 u = XL4[(size_t)v * 64 + 32 + li];
        xr[0] = __uint_as_float(u.x << 16);  xr[1] = __uint_as_float(u.x & 0xffff0000u);
        xr[2] = __uint_as_float(u.y << 16);  xr[3] = __uint_as_float(u.y & 0xffff0000u);
        xr[4] = __uint_as_float(u.z << 16);  xr[5] = __uint_as_float(u.z & 0xffff0000u);
        xr[6] = __uint_as_float(u.w << 16);  xr[7] = __uint_as_float(u.w & 0xffff0000u);
    }
    float z = 0.f;
    float acc[8] = {};
    const int e0 = offs[v], e1 = offs[v + 1];
    for (int j0 = e0; j0 < e1; j0 += 4) {
        #pragma unroll
        for (int p = 0; p < 2; ++p) {
            int j = j0 + p * 2 + half;
            bool valid = (j < e1);
            int jj = valid ? j : (e1 - 1);
            int src = csr[jj];
            uint4 u = XL4[(size_t)src * 64 + li];
            float f[8];
            f[0] = __uint_as_float(u.x << 16);  f[1] = __uint_as_float(u.x & 0xffff0000u);
            f[2] = __uint_as_float(u.y << 16);  f[3] = __uint_as_float(u.y & 0xffff0000u);
            f[4] = __uint_as_float(u.z << 16);  f[5] = __uint_as_float(u.z & 0xffff0000u);
            f[6] = __uint_as_float(u.w << 16);  f[7] = __uint_as_float(u.w & 0xffff0000u);
            float s1 = 0.f, s2 = 0.f;
            #pragma unroll
            for (int k = 0; k < 8; ++k) {
                float t = f[k] + xr[k];
                s1 = fmaf(t, av[k], s1);
                s2 = fmaf(fabsf(t), av[k], s2);
            }
            float s = fmaf(0.6f, s1, 0.4f * s2);
            s += __shfl_xor(s, 1);
            s += __shfl_xor(s, 2);
            float w = valid ? __expf(s) : 0.f;
            z += w;
            #pragma unroll
            for (int k = 0; k < 8; ++k) acc[k] = fmaf(w, f[k], acc[k]);
        }
    }
    z += __shfl_xor(z, 32);
    #pragma unroll
    for (int k = 0; k < 8; ++k) acc[k] += __shfl_xor(acc[k], 32);
    if (half == 0) {
        const float rz = 1.f / z;
        unsigned int o[4];
        #pragma unroll
        for (int k2 = 0; k2 < 4; ++k2) {
            float lo = fmaf(acc[k2 * 2 + 0], rz, bias[li * 8 + k2 * 2 + 0]);
            float hi = fmaf(acc[k2 * 2 + 1], rz, bias[li * 8 + k2 * 2 + 1]);
            lo = (lo > 0.f) ? lo : (__expf(lo) - 1.f);
            hi = (hi > 0.f) ? hi : (__expf(hi) - 1.f);
            o[k2] = (unsigned int)f2bf(lo) | ((unsigned int)f2bf(hi) << 16);
        }
        uint4 ov = { o[0], o[1], o[2], o[3] };
        *(uint4*)(out + (size_t)v * 256 + li * 8) = ov;
    }
}

// ---------------------------------------------------------------------------
// Layer-2 edge pass: one wave per block. XLR[N,128] bf16: cols 0..63 = xl,
// 64..127 = xr. lane li (0..7) owns 8 ch; slot = lane>>3.
// ---------------------------------------------------------------------------
__global__ __launch_bounds__(64)
void k_edge2(const unsigned short* __restrict__ XLR,
             const int* __restrict__ offs, const int* __restrict__ csr,
             const float* __restrict__ att, const float* __restrict__ bias,
             float* __restrict__ out, int n) {
    const int lane = threadIdx.x;
    const int v = blockIdx.x;
    const int li = lane & 7;
    const int slot = lane >> 3;
    const uint4* XL4 = (const uint4*)XLR;   // row = 16 uint4 (128 bf16)
    float av[8], xr[8];
    #pragma unroll
    for (int k = 0; k < 8; ++k) av[k] = att[li * 8 + k];
    {
        uint4 u = XL4[(size_t)v * 16 + 8 + li];
        xr[0] = __uint_as_float(u.x << 16);  xr[1] = __uint_as_float(u.x & 0xffff0000u);
        xr[2] = __uint_as_float(u.y << 16);  xr[3] = __uint_as_float(u.y & 0xffff0000u);
        xr[4] = __uint_as_float(u.z << 16);  xr[5] = __uint_as_float(u.z & 0xffff0000u);
        xr[6] = __uint_as_float(u.w << 16);  xr[7] = __uint_as_float(u.w & 0xffff0000u);
    }
    float z = 0.f;
    float acc[8] = {};
    const int e0 = offs[v], e1 = offs[v + 1];
    for (int j0 = e0; j0 < e1; j0 += 8) {
        int j = j0 + slot;
        bool valid = (j < e1);
        int jj = valid ? j : (e1 - 1);
        int src = csr[jj];
        uint4 u = XL4[(size_t)src * 16 + li];
        float f[8];
        f[0] = __uint_as_float(u.x << 16);  f[1] = __uint_as_float(u.x & 0xffff0000u);
        f[2] = __uint_as_float(u.y << 16);  f[3] = __uint_as_float(u.y & 0xffff0000u);
        f[4] = __uint_as_float(u.z << 16);  f[5] = __uint_as_float(u.z & 0xffff0000u);
        f[6] = __uint_as_float(u.w << 16);  f[7] = __uint_as_float(u.w & 0xffff0000u);
        float s1 = 0.f, s2 = 0.f;
        #pragma unroll
        for (int k = 0; k < 8; ++k) {
            float t = f[k] + xr[k];
            s1 = fmaf(t, av[k], s1);
            s2 = fmaf(fabsf(t), av[k], s2);
        }
        float s = fmaf(0.6f, s1, 0.4f * s2);
        s += __shfl_xor(s, 1);
        s += __shfl_xor(s, 2);
        float w = valid ? __expf(s) : 0.f;
        z += w;
        #pragma unroll
        for (int k = 0; k < 8; ++k) acc[k] = fmaf(w, f[k], acc[k]);
    }
    z += __shfl_xor(z, 8);  z += __shfl_xor(z, 16);  z += __shfl_xor(z, 32);
    #pragma unroll
    for (int k = 0; k < 8; ++k) {
        acc[k] += __shfl_xor(acc[k], 8);
        acc[k] += __shfl_xor(acc[k], 16);
        acc[k] += __shfl_xor(acc[k], 32);
    }
    if (slot == 0) {
        const float rz = 1.f / z;
        float o[8];
        #pragma unroll
        for (int k = 0; k < 8; ++k)
            o[k] = fmaf(acc[k], rz, bias[li * 8 + k]);
        float4 o0 = { o[0], o[1], o[2], o[3] };
        float4 o1 = { o[4], o[5], o[6], o[7] };
        *(float4*)(out + (size_t)v * 64 + li * 8 + 0) = o0;
        *(float4*)(out + (size_t)v * 64 + li * 8 + 4) = o1;
    }
}

// ---------------------------------------------------------------------------
// Fused mean-pool + MLP head: one block per graph.
// ---------------------------------------------------------------------------
__global__ __launch_bounds__(256)
void k_pool_mlp(const float* __restrict__ out2, const int* __restrict__ batch,
                const float* __restrict__ fc1w, const float* __restrict__ fc1b,
                const float* __restrict__ fc2w, const float* __restrict__ fc2b,
                const float* __restrict__ fcw,  const float* __restrict__ fcb,
                float* __restrict__ outc, float* __restrict__ outx2, int n) {
    const int g = blockIdx.x;
    const int t = threadIdx.x;
    const int lane = t & 63;
    const int w = t >> 6;
    __shared__ float red[4][64];
    __shared__ float hg_s[64];
    __shared__ float x1_s[32];
    __shared__ float x2_s[16];

    int lo = 0, hi = n;
    while (lo < hi) { int mid = (lo + hi) >> 1; if (batch[mid] < g) lo = mid + 1; else hi = mid; }
    const int start = lo;
    hi = n;
    while (lo < hi) { int mid = (lo + hi) >> 1; if (batch[mid] < g + 1) lo = mid + 1; else hi = mid; }
    const int end = lo;

    float s = 0.f;
    for (int v = start + w; v < end; v += 4)
        s += out2[(size_t)v * 64 + lane];
    red[w][lane] = s;
    __syncthreads();
    if (w == 0) {
        float tot = red[0][lane] + red[1][lane] + red[2][lane] + red[3][lane];
        float cnt = fmaxf((float)(end - start), 1.0f);
        hg_s[lane] = tot / cnt;
    }
    __syncthreads();
    if (t < 32) {
        float a = fc1b[t];
        #pragma unroll
        for (int k = 0; k < 64; ++k) a = fmaf(hg_s[k], fc1w[k * 32 + t], a);
        x1_s[t] = fmaxf(a, 0.f);
    }
    __syncthreads();
    if (t < 16) {
        float a = fc2b[t];
        #pragma unroll
        for (int k = 0; k < 32; ++k) a = fmaf(x1_s[k], fc2w[k * 16 + t], a);
        x2_s[t] = fmaxf(a, 0.f);
    }
    __syncthreads();
    if (t < DOUT) {
        float a = fcb[t];
        #pragma unroll
        for (int k = 0; k < 16; ++k) a = fmaf(x2_s[k], fcw[k * 10 + t], a);
        outc[g * DOUT + t] = a;
    }
    if (t < 16) outx2[g * 16 + t] = x2_s[t];
}

// ---------------------------------------------------------------------------
extern "C" void kernel_launch(void* const* d_in, const int* in_sizes, int n_in,
                              void* d_out, int out_size, void* d_ws, size_t ws_size,
                              hipStream_t stream) {
    const float* x    = (const float*)d_in[0];
    const int*   ei   = (const int*)d_in[1];
    const int*   batch= (const int*)d_in[2];
    const float* W1l  = (const float*)d_in[3];
    const float* W1r  = (const float*)d_in[4];
    const float* a1   = (const float*)d_in[5];
    const float* b1   = (const float*)d_in[6];
    const float* W2l  = (const float*)d_in[7];
    const float* W2r  = (const float*)d_in[8];
    const float* a2   = (const float*)d_in[9];
    const float* b2   = (const float*)d_in[10];
    const float* fc1w = (const float*)d_in[11];
    const float* fc1b = (const float*)d_in[12];
    const float* fc2w = (const float*)d_in[13];
    const float* fc2b = (const float*)d_in[14];
    const float* fcw  = (const float*)d_in[15];
    const float* fcb  = (const float*)d_in[16];

    const int N = in_sizes[2];          // 30000
    const int E = in_sizes[1] / 2;      // 480000
    const int ET = E + N;
    const int* esrc = ei;
    const int* edst = ei + E;
    const int NB = (N + SCAN_B - 1) / SCAN_B;   // 59 (<=64)

    // workspace layout
    char* ws = (char*)d_ws;
    size_t off = 0;
    unsigned short* xlr1b = (unsigned short*)(ws + off); off += (size_t)N * 512 * 2;  // [N,512] xl|xr bf16
    unsigned short* h1b  = (unsigned short*)(ws + off);  off += (size_t)N * 256 * 2;  // [N,256] bf16
    float* out2 = (float*)(ws + off);            off += (size_t)N * 64 * 4;           // [N,64] f32
    int*   deg   = (int*)(ws + off);             off += ((size_t)(N + 1) * 4 + 255) & ~255ull;
    int*   cursor= (int*)(ws + off);             off += ((size_t)N * 4 + 255) & ~255ull;
    int*   csr   = (int*)(ws + off);             off += ((size_t)ET * 4 + 255) & ~255ull;
    int*   bsum  = (int*)(ws + off);             off += ((size_t)(NB + 1) * 4 + 255) & ~255ull;
    short* B1th  = (short*)(ws + off);           off += (size_t)512 * 128 * 2;
    short* B1tl  = (short*)(ws + off);           off += (size_t)512 * 128 * 2;
    short* B2th  = (short*)(ws + off);           off += (size_t)128 * 256 * 2;
    short* B2tl  = (short*)(ws + off);           off += (size_t)128 * 256 * 2;
    unsigned short* xg = (unsigned short*)(ws + off); off += (size_t)N * 256 * 2;     // [N,256] hi|lo bf16
    unsigned short* xlr2b = xlr1b;               // [N,128] bf16 (reuse)
    (void)ws_size; (void)n_in; (void)out_size;

    float* outc  = (float*)d_out;
    float* outx2 = (float*)d_out + GNUM * DOUT;

    // Prep: zero deg + split x to bf16 hi/lo + split weights
    const int prep_tot = N * 32 + 512 * 128 + 128 * 256;
    k_prep<<<(prep_tot + 255) / 256, 256, 0, stream>>>(
        x, W1l, W1r, W2l, W2r, xg, B1th, B1tl, B2th, B2tl, deg, N + 1, N);

    // CSR build
    int tb = 256;
    int gb = (ET + tb - 1) / tb;
    k_deg<<<gb, tb, 0, stream>>>(edst, deg, E, N);
    k_scan_partial<<<NB, SCAN_B, 0, stream>>>(deg, bsum, N);
    k_scan_apply<<<NB, SCAN_B, 0, stream>>>(deg, cursor, bsum, N, NB);
    k_scatter<<<gb, tb, 0, stream>>>(esrc, edst, cursor, csr, E, N);

    // Layer 1 GEMM (no-LDS main loop, all-bf16 output): xlr1b[N,512]
    dim3 g1((N + 127) / 128, 4);
    k_gemm1<<<g1, 256, 0, stream>>>(xg, B1th, B1tl, xlr1b, N, 512);

    // Layer 1 edge pass -> h1b bf16
    k_edge1<<<N, 64, 0, stream>>>(xlr1b, deg, csr, a1, b1, h1b, N);

    // Layer 2 GEMM (no-LDS, 128x64 tiles): xlr2b[N,128]
    dim3 g2((N + 127) / 128, 2);
    k_gemm_bf<<<g2, 256, 0, stream>>>(h1b, B2th, B2tl, xlr2b, N, 128);

    // Layer 2 edge pass -> out2 (f32)
    k_edge2<<<N, 64, 0, stream>>>(xlr2b, deg, csr, a2, b2, out2, N);

    // Fused pool + MLP
    k_pool_mlp<<<GNUM, 256, 0, stream>>>(out2, batch, fc1w, fc1b, fc2w, fc2b,
                                         fcw, fcb, outc, outx2, N);
}

// Round 2
// 282.213 us; speedup vs baseline: 1.0483x; 1.0483x over previous
//
#include <hip/hip_runtime.h>
#include <math.h>

#define DIN 128
#define DH  32
#define H1  8
#define H2  2
#define GNUM 64
#define DOUT 10
#define NEG_SLOPE 0.2f
#define SCAN_B 512

typedef __attribute__((ext_vector_type(8))) short sv8;
typedef __attribute__((ext_vector_type(4))) float fv4;

static __device__ __forceinline__ unsigned short f2bf(float f) {
    unsigned int u = __float_as_uint(f);
    unsigned int r = (u + 0x7fffu + ((u >> 16) & 1u)) >> 16;
    return (unsigned short)r;
}
static __device__ __forceinline__ float bf2f(unsigned short h) {
    return __uint_as_float(((unsigned int)h) << 16);
}

// Packed fragment layout for MFMA operands:
//   element (row, k) lives at ((row/16 * NC + k/32) * 64 + ((k>>3)&3)*16 + (row&15)) * 8 + (k&7)
// where NC = K/32. A wave's fragment load for (rowgroup R, kchunk c) is then
//   base + ((R*NC + c)*64 + lane)*8   -- lane-contiguous 16B => fully coalesced.

// ---------------------------------------------------------------------------
// Prep: zero deg, split x -> bf16 hi|lo PACKED, transpose+split W1/W2 PACKED
// ---------------------------------------------------------------------------
__global__ void k_prep(const float* __restrict__ x,
                       const float* __restrict__ W1l, const float* __restrict__ W1r,
                       const float* __restrict__ W2l, const float* __restrict__ W2r,
                       unsigned short* __restrict__ xgh, unsigned short* __restrict__ xgl,
                       short* __restrict__ B1th, short* __restrict__ B1tl,
                       short* __restrict__ B2th, short* __restrict__ B2tl,
                       int* __restrict__ zbase, int nz, int n) {
    int id = blockIdx.x * blockDim.x + threadIdx.x;
    if (id < nz) zbase[id] = 0;        // deg[N+1]
    const int NX = n * 32;             // 32 threads per row of x
    const int T1 = 512 * 128;
    const int T2 = 128 * 256;
    if (id < NX) {
        int m = id >> 5, j4 = id & 31;           // k = j4*4
        float4 v = *(const float4*)(x + (size_t)m * 128 + j4 * 4);
        unsigned short hx = f2bf(v.x), hy = f2bf(v.y), hz = f2bf(v.z), hw = f2bf(v.w);
        ushort4 hi; hi.x = hx; hi.y = hy; hi.z = hz; hi.w = hw;
        ushort4 lo;
        lo.x = f2bf(v.x - bf2f(hx)); lo.y = f2bf(v.y - bf2f(hy));
        lo.z = f2bf(v.z - bf2f(hz)); lo.w = f2bf(v.w - bf2f(hw));
        int R = m >> 4, r = m & 15;
        int C = j4 >> 3, q = (j4 >> 1) & 3, j = (j4 & 1) * 4;
        size_t o = ((size_t)(R * 4 + C) * 64 + q * 16 + r) * 8 + j;
        *(ushort4*)(xgh + o) = hi;
        *(ushort4*)(xgl + o) = lo;
    } else if (id < NX + T1) {
        int id1 = id - NX;
        int nn = id1 / 128, k = id1 - nn * 128;   // nn: out-channel (512), k: K (128)
        float v = (nn < 256) ? W1l[(size_t)k * 256 + nn] : W1r[(size_t)k * 256 + (nn - 256)];
        unsigned short h = f2bf(v);
        size_t o = (((size_t)(nn >> 4) * 4 + (k >> 5)) * 64 + ((k >> 3) & 3) * 16 + (nn & 15)) * 8 + (k & 7);
        B1th[o] = (short)h;
        B1tl[o] = (short)f2bf(v - bf2f(h));
    } else if (id < NX + T1 + T2) {
        int id2 = id - NX - T1;
        int nn = id2 / 256, k = id2 - nn * 256;   // nn: out-channel (128), k: K (256)
        float v = (nn < 64) ? W2l[(size_t)k * 64 + nn] : W2r[(size_t)k * 64 + (nn - 64)];
        unsigned short h = f2bf(v);
        size_t o = (((size_t)(nn >> 4) * 8 + (k >> 5)) * 64 + ((k >> 3) & 3) * 16 + (nn & 15)) * 8 + (k & 7);
        B2th[o] = (short)h;
        B2tl[o] = (short)f2bf(v - bf2f(h));
    }
}

// ---------------------------------------------------------------------------
// CSR build
// ---------------------------------------------------------------------------
__global__ void k_deg(const int* __restrict__ dst, int* __restrict__ deg, int E, int n) {
    int i = blockIdx.x * blockDim.x + threadIdx.x;
    if (i < E) {
        atomicAdd(&deg[dst[i]], 1);
    } else if (i < E + n) {
        atomicAdd(&deg[i - E], 1);   // self loop
    }
}

__global__ __launch_bounds__(SCAN_B)
void k_scan_partial(const int* __restrict__ deg, int* __restrict__ bsum, int n) {
    int i = blockIdx.x * SCAN_B + threadIdx.x;
    int v = (i < n) ? deg[i] : 0;
    #pragma unroll
    for (int m = 32; m >= 1; m >>= 1) v += __shfl_xor(v, m);
    __shared__ int red[SCAN_B / 64];
    if ((threadIdx.x & 63) == 0) red[threadIdx.x >> 6] = v;
    __syncthreads();
    if (threadIdx.x == 0) {
        int s = 0;
        #pragma unroll
        for (int k = 0; k < SCAN_B / 64; ++k) s += red[k];
        bsum[blockIdx.x] = s;
    }
}

__global__ __launch_bounds__(SCAN_B)
void k_scan_apply(int* __restrict__ deg, int* __restrict__ cursor,
                  const int* __restrict__ bsum, int n, int nb) {
    __shared__ int buf[SCAN_B];
    __shared__ int pfx_s, tot_s;
    const int t = threadIdx.x, b = blockIdx.x;
    if (t < 64) {
        int v = (t < nb) ? bsum[t] : 0;
        int incl = v;
        #pragma unroll
        for (int o = 1; o < 64; o <<= 1) {
            int w = __shfl_up(incl, o);
            if (t >= o) incl += w;
        }
        int pfx = (b == 0) ? 0 : __shfl(incl, b - 1);
        int tot = __shfl(incl, nb - 1);
        if (t == 0) { pfx_s = pfx; tot_s = tot; }
    }
    int i = b * SCAN_B + t;
    int v = (i < n) ? deg[i] : 0;
    buf[t] = v;
    __syncthreads();
    for (int o = 1; o < SCAN_B; o <<= 1) {
        int a = (t >= o) ? buf[t - o] : 0;
        __syncthreads();
        buf[t] += a;
        __syncthreads();
    }
    int excl = buf[t] - v + pfx_s;
    if (i < n) { deg[i] = excl; cursor[i] = excl; }
    if (b == 0 && t == 0) deg[n] = tot_s;
}

__global__ void k_scatter(const int* __restrict__ src, const int* __restrict__ dst,
                          int* __restrict__ cursor, int* __restrict__ csr_src, int E, int n) {
    int i = blockIdx.x * blockDim.x + threadIdx.x;
    if (i < E) {
        int d = dst[i];
        int pos = atomicAdd(&cursor[d], 1);
        csr_src[pos] = src[i];
    } else if (i < E + n) {
        int v = i - E;
        int pos = atomicAdd(&cursor[v], 1);
        csr_src[pos] = v;   // self loop
    }
}

// ---------------------------------------------------------------------------
// Layer-1 GEMM: packed-fragment operands, fully coalesced lane-contiguous
// loads, zero K-loop barriers, zero LDS in main loop.
// A: xgh/xgl packed [M/16][4][64][8]; B: B1th/B1tl packed [32][4][64][8].
// 3 products: Ah*Bh + Ah*Bl + Al*Bh.
// ---------------------------------------------------------------------------
__global__ __launch_bounds__(256, 2)
void k_gemm1(const unsigned short* __restrict__ Ah, const unsigned short* __restrict__ Al,
             const short* __restrict__ Bth, const short* __restrict__ Btl,
             unsigned short* __restrict__ C,
             int M, int Ntot) {
    __shared__ float smc[64 * 68];
    const int tid = threadIdx.x;
    const int lane = tid & 63;
    const int wid = tid >> 6;
    const int wm = wid & 1, wn = wid >> 1;
    const int m0 = blockIdx.x * 128;
    const int n0 = blockIdx.y * 128;
    const int l15 = lane & 15, q = lane >> 4;
    const int MR = (M >> 4) - 1;

    fv4 acc[4][4] = {};

    const unsigned short* ap[4];
    const unsigned short* alp[4];
    #pragma unroll
    for (int fm = 0; fm < 4; ++fm) {
        int R = (m0 >> 4) + wm * 4 + fm;
        if (R > MR) R = MR;                      // tail clamp; stores guarded
        ap[fm]  = Ah + ((size_t)R * 4 * 64 + lane) * 8;
        alp[fm] = Al + ((size_t)R * 4 * 64 + lane) * 8;
    }
    const short* bhp[4];
    const short* blp[4];
    #pragma unroll
    for (int fn = 0; fn < 4; ++fn) {
        int R = (n0 >> 4) + wn * 4 + fn;
        bhp[fn] = Bth + ((size_t)R * 4 * 64 + lane) * 8;
        blp[fn] = Btl + ((size_t)R * 4 * 64 + lane) * 8;
    }

    #pragma unroll
    for (int c = 0; c < 4; ++c) {
        const size_t co = (size_t)c * 512;       // 64 lanes * 8 elems
        sv8 ah[4], al[4], bh[4], bl[4];
        #pragma unroll
        for (int fn = 0; fn < 4; ++fn) {
            bh[fn] = *(const sv8*)(bhp[fn] + co);
            bl[fn] = *(const sv8*)(blp[fn] + co);
        }
        #pragma unroll
        for (int fm = 0; fm < 4; ++fm) {
            ah[fm] = *(const sv8*)(ap[fm] + co);
            al[fm] = *(const sv8*)(alp[fm] + co);
        }
        #pragma unroll
        for (int fm = 0; fm < 4; ++fm) {
            #pragma unroll
            for (int fn = 0; fn < 4; ++fn) {
                acc[fm][fn] = __builtin_amdgcn_mfma_f32_16x16x32_bf16(ah[fm], bh[fn], acc[fm][fn], 0, 0, 0);
                acc[fm][fn] = __builtin_amdgcn_mfma_f32_16x16x32_bf16(ah[fm], bl[fn], acc[fm][fn], 0, 0, 0);
                acc[fm][fn] = __builtin_amdgcn_mfma_f32_16x16x32_bf16(al[fm], bh[fn], acc[fm][fn], 0, 0, 0);
            }
        }
    }

    // epilogue: 4 slices (row-half s x col-half cn), 64x64 each, bf16 only
    #pragma unroll
    for (int s = 0; s < 2; ++s) {
        #pragma unroll
        for (int cn = 0; cn < 2; ++cn) {
            __syncthreads();
            if (wm == s && wn == cn) {
                #pragma unroll
                for (int fm = 0; fm < 4; ++fm)
                    #pragma unroll
                    for (int fn = 0; fn < 4; ++fn)
                        #pragma unroll
                        for (int r = 0; r < 4; ++r)
                            smc[(fm * 16 + q * 4 + r) * 68 + fn * 16 + l15] = acc[fm][fn][r];
            }
            __syncthreads();
            int lr = tid >> 2;              // 0..63
            int grow = m0 + s * 64 + lr;
            if (grow < M) {
                #pragma unroll
                for (int k4 = 0; k4 < 4; ++k4) {
                    int jj = (tid & 3) + k4 * 4;    // 0..15 float4 index
                    float4 vv = *(float4*)&smc[lr * 68 + jj * 4];
                    int gcol = n0 + cn * 64 + jj * 4;
                    ushort4 uu;
                    uu.x = f2bf(vv.x); uu.y = f2bf(vv.y);
                    uu.z = f2bf(vv.z); uu.w = f2bf(vv.w);
                    *(ushort4*)(C + (size_t)grow * Ntot + gcol) = uu;
                }
            }
        }
    }
}

// ---------------------------------------------------------------------------
// Layer-2 GEMM: packed-fragment operands, K=256 (NC=8), tile 128x64.
// A: h1b packed [M/16][8][64][8]; B: B2th/B2tl packed [8][8][64][8].
// ---------------------------------------------------------------------------
__global__ __launch_bounds__(256, 2)
void k_gemm_bf(const unsigned short* __restrict__ A, const short* __restrict__ Bth,
               const short* __restrict__ Btl,
               unsigned short* __restrict__ C,
               int M, int Ntot) {
    __shared__ float smc[64 * 36];
    const int tid = threadIdx.x;
    const int lane = tid & 63;
    const int wid = tid >> 6;
    const int wm = wid & 1, wn = wid >> 1;   // wn in {0,1}: 32-col halves
    const int m0 = blockIdx.x * 128;
    const int n0 = blockIdx.y * 64;
    const int l15 = lane & 15, q = lane >> 4;
    const int MR = (M >> 4) - 1;

    fv4 acc[4][2] = {};

    const unsigned short* ap[4];
    #pragma unroll
    for (int fm = 0; fm < 4; ++fm) {
        int R = (m0 >> 4) + wm * 4 + fm;
        if (R > MR) R = MR;
        ap[fm] = A + ((size_t)R * 8 * 64 + lane) * 8;
    }
    const short* bhp[2];
    const short* blp[2];
    #pragma unroll
    for (int fn = 0; fn < 2; ++fn) {
        int R = (n0 >> 4) + wn * 2 + fn;
        bhp[fn] = Bth + ((size_t)R * 8 * 64 + lane) * 8;
        blp[fn] = Btl + ((size_t)R * 8 * 64 + lane) * 8;
    }

    #pragma unroll 4
    for (int c = 0; c < 8; ++c) {
        const size_t co = (size_t)c * 512;
        sv8 ah[4], bh[2], bl[2];
        #pragma unroll
        for (int fn = 0; fn < 2; ++fn) {
            bh[fn] = *(const sv8*)(bhp[fn] + co);
            bl[fn] = *(const sv8*)(blp[fn] + co);
        }
        #pragma unroll
        for (int fm = 0; fm < 4; ++fm)
            ah[fm] = *(const sv8*)(ap[fm] + co);
        #pragma unroll
        for (int fm = 0; fm < 4; ++fm) {
            #pragma unroll
            for (int fn = 0; fn < 2; ++fn) {
                acc[fm][fn] = __builtin_amdgcn_mfma_f32_16x16x32_bf16(ah[fm], bh[fn], acc[fm][fn], 0, 0, 0);
                acc[fm][fn] = __builtin_amdgcn_mfma_f32_16x16x32_bf16(ah[fm], bl[fn], acc[fm][fn], 0, 0, 0);
            }
        }
    }

    // epilogue: 4 slices (row-half s x col-half cn), 64x32 each
    #pragma unroll
    for (int s = 0; s < 2; ++s) {
        #pragma unroll
        for (int cn = 0; cn < 2; ++cn) {
            __syncthreads();
            if (wm == s && wn == cn) {
                #pragma unroll
                for (int fm = 0; fm < 4; ++fm)
                    #pragma unroll
                    for (int fn = 0; fn < 2; ++fn)
                        #pragma unroll
                        for (int r = 0; r < 4; ++r)
                            smc[(fm * 16 + q * 4 + r) * 36 + fn * 16 + l15] = acc[fm][fn][r];
            }
            __syncthreads();
            int lr = tid >> 2;              // 0..63
            int grow = m0 + s * 64 + lr;
            if (grow < M) {
                #pragma unroll
                for (int k4 = 0; k4 < 2; ++k4) {
                    int jj = (tid & 3) + k4 * 4;    // 0..7 float4 index
                    float4 vv = *(float4*)&smc[lr * 36 + jj * 4];
                    int gcol = n0 + cn * 32 + jj * 4;
                    ushort4 uu;
                    uu.x = f2bf(vv.x); uu.y = f2bf(vv.y);
                    uu.z = f2bf(vv.z); uu.w = f2bf(vv.w);
                    *(ushort4*)(C + (size_t)grow * Ntot + gcol) = uu;
                }
            }
        }
    }
}

// ---------------------------------------------------------------------------
// Layer-1 edge pass: one wave per block. XLR[N,512] bf16: cols 0..255 = xl,
// 256..511 = xr. lane li (0..31) owns 8 ch; half = edge slot.
// Output h1b written in PACKED fragment layout for gemm_bf.
// ---------------------------------------------------------------------------
__global__ __launch_bounds__(64)
void k_edge1(const unsigned short* __restrict__ XLR,
             const int* __restrict__ offs, const int* __restrict__ csr,
             const float* __restrict__ att, const float* __restrict__ bias,
             unsigned short* __restrict__ out, int n) {
    const int lane = threadIdx.x;
    const int v = blockIdx.x;
    const int li = lane & 31;
    const int half = lane >> 5;
    const uint4* XL4 = (const uint4*)XLR;   // row = 64 uint4 (512 bf16)
    float av[8], xr[8];
    #pragma unroll
    for (int k = 0; k < 8; ++k) av[k] = att[li * 8 + k];
    {
        uint4 u = XL4[(size_t)v * 64 + 32 + li];
        xr[0] = __uint_as_float(u.x << 16);  xr[1] = __uint_as_float(u.x & 0xffff0000u);
        xr[2] = __uint_as_float(u.y << 16);  xr[3] = __uint_as_float(u.y & 0xffff0000u);
        xr[4] = __uint_as_float(u.z << 16);  xr[5] = __uint_as_float(u.z & 0xffff0000u);
        xr[6] = __uint_as_float(u.w << 16);  xr[7] = __uint_as_float(u.w & 0xffff0000u);
    }
    float z = 0.f;
    float acc[8] = {};
    const int e0 = offs[v], e1 = offs[v + 1];
    for (int j0 = e0; j0 < e1; j0 += 4) {
        #pragma unroll
        for (int p = 0; p < 2; ++p) {
            int j = j0 + p * 2 + half;
            bool valid = (j < e1);
            int jj = valid ? j : (e1 - 1);
            int src = csr[jj];
            uint4 u = XL4[(size_t)src * 64 + li];
            float f[8];
            f[0] = __uint_as_float(u.x << 16);  f[1] = __uint_as_float(u.x & 0xffff0000u);
            f[2] = __uint_as_float(u.y << 16);  f[3] = __uint_as_float(u.y & 0xffff0000u);
            f[4] = __uint_as_float(u.z << 16);  f[5] = __uint_as_float(u.z & 0xffff0000u);
            f[6] = __uint_as_float(u.w << 16);  f[7] = __uint_as_float(u.w & 0xffff0000u);
            float s1 = 0.f, s2 = 0.f;
            #pragma unroll
            for (int k = 0; k < 8; ++k) {
                float t = f[k] + xr[k];
                s1 = fmaf(t, av[k], s1);
                s2 = fmaf(fabsf(t), av[k], s2);
            }
            float s = fmaf(0.6f, s1, 0.4f * s2);
            s += __shfl_xor(s, 1);
            s += __shfl_xor(s, 2);
            float w = valid ? __expf(s) : 0.f;
            z += w;
            #pragma unroll
            for (int k = 0; k < 8; ++k) acc[k] = fmaf(w, f[k], acc[k]);
        }
    }
    z += __shfl_xor(z, 32);
    #pragma unroll
    for (int k = 0; k < 8; ++k) acc[k] += __shfl_xor(acc[k], 32);
    if (half == 0) {
        const float rz = 1.f / z;
        unsigned int o[4];
        #pragma unroll
        for (int k2 = 0; k2 < 4; ++k2) {
            float lo = fmaf(acc[k2 * 2 + 0], rz, bias[li * 8 + k2 * 2 + 0]);
            float hi = fmaf(acc[k2 * 2 + 1], rz, bias[li * 8 + k2 * 2 + 1]);
            lo = (lo > 0.f) ? lo : (__expf(lo) - 1.f);
            hi = (hi > 0.f) ? hi : (__expf(hi) - 1.f);
            o[k2] = (unsigned int)f2bf(lo) | ((unsigned int)f2bf(hi) << 16);
        }
        uint4 ov = { o[0], o[1], o[2], o[3] };
        // packed fragment layout: R=v>>4, C=li>>2, lane=(li&3)*16+(v&15)
        size_t po = (((size_t)(v >> 4) * 8 + (li >> 2)) * 64 + (li & 3) * 16 + (v & 15)) * 8;
        *(uint4*)(out + po) = ov;
    }
}

// ---------------------------------------------------------------------------
// Layer-2 edge pass: one wave per block. XLR[N,128] bf16: cols 0..63 = xl,
// 64..127 = xr. lane li (0..7) owns 8 ch; slot = lane>>3.
// ---------------------------------------------------------------------------
__global__ __launch_bounds__(64)
void k_edge2(const unsigned short* __restrict__ XLR,
             const int* __restrict__ offs, const int* __restrict__ csr,
             const float* __restrict__ att, const float* __restrict__ bias,
             float* __restrict__ out, int n) {
    const int lane = threadIdx.x;
    const int v = blockIdx.x;
    const int li = lane & 7;
    const int slot = lane >> 3;
    const uint4* XL4 = (const uint4*)XLR;   // row = 16 uint4 (128 bf16)
    float av[8], xr[8];
    #pragma unroll
    for (int k = 0; k < 8; ++k) av[k] = att[li * 8 + k];
    {
        uint4 u = XL4[(size_t)v * 16 + 8 + li];
        xr[0] = __uint_as_float(u.x << 16);  xr[1] = __uint_as_float(u.x & 0xffff0000u);
        xr[2] = __uint_as_float(u.y << 16);  xr[3] = __uint_as_float(u.y & 0xffff0000u);
        xr[4] = __uint_as_float(u.z << 16);  xr[5] = __uint_as_float(u.z & 0xffff0000u);
        xr[6] = __uint_as_float(u.w << 16);  xr[7] = __uint_as_float(u.w & 0xffff0000u);
    }
    float z = 0.f;
    float acc[8] = {};
    const int e0 = offs[v], e1 = offs[v + 1];
    for (int j0 = e0; j0 < e1; j0 += 8) {
        int j = j0 + slot;
        bool valid = (j < e1);
        int jj = valid ? j : (e1 - 1);
        int src = csr[jj];
        uint4 u = XL4[(size_t)src * 16 + li];
        float f[8];
        f[0] = __uint_as_float(u.x << 16);  f[1] = __uint_as_float(u.x & 0xffff0000u);
        f[2] = __uint_as_float(u.y << 16);  f[3] = __uint_as_float(u.y & 0xffff0000u);
        f[4] = __uint_as_float(u.z << 16);  f[5] = __uint_as_float(u.z & 0xffff0000u);
        f[6] = __uint_as_float(u.w << 16);  f[7] = __uint_as_float(u.w & 0xffff0000u);
        float s1 = 0.f, s2 = 0.f;
        #pragma unroll
        for (int k = 0; k < 8; ++k) {
            float t = f[k] + xr[k];
            s1 = fmaf(t, av[k], s1);
            s2 = fmaf(fabsf(t), av[k], s2);
        }
        float s = fmaf(0.6f, s1, 0.4f * s2);
        s += __shfl_xor(s, 1);
        s += __shfl_xor(s, 2);
        float w = valid ? __expf(s) : 0.f;
        z += w;
        #pragma unroll
        for (int k = 0; k < 8; ++k) acc[k] = fmaf(w, f[k], acc[k]);
    }
    z += __shfl_xor(z, 8);  z += __shfl_xor(z, 16);  z += __shfl_xor(z, 32);
    #pragma unroll
    for (int k = 0; k < 8; ++k) {
        acc[k] += __shfl_xor(acc[k], 8);
        acc[k] += __shfl_xor(acc[k], 16);
        acc[k] += __shfl_xor(acc[k], 32);
    }
    if (slot == 0) {
        const float rz = 1.f / z;
        float o[8];
        #pragma unroll
        for (int k = 0; k < 8; ++k)
            o[k] = fmaf(acc[k], rz, bias[li * 8 + k]);
        float4 o0 = { o[0], o[1], o[2], o[3] };
        float4 o1 = { o[4], o[5], o[6], o[7] };
        *(float4*)(out + (size_t)v * 64 + li * 8 + 0) = o0;
        *(float4*)(out + (size_t)v * 64 + li * 8 + 4) = o1;
    }
}

// ---------------------------------------------------------------------------
// Fused mean-pool + MLP head: one block per graph.
// ---------------------------------------------------------------------------
__global__ __launch_bounds__(256)
void k_pool_mlp(const float* __restrict__ out2, const int* __restrict__ batch,
                const float* __restrict__ fc1w, const float* __restrict__ fc1b,
                const float* __restrict__ fc2w, const float* __restrict__ fc2b,
                const float* __restrict__ fcw,  const float* __restrict__ fcb,
                float* __restrict__ outc, float* __restrict__ outx2, int n) {
    const int g = blockIdx.x;
    const int t = threadIdx.x;
    const int lane = t & 63;
    const int w = t >> 6;
    __shared__ float red[4][64];
    __shared__ float hg_s[64];
    __shared__ float x1_s[32];
    __shared__ float x2_s[16];

    int lo = 0, hi = n;
    while (lo < hi) { int mid = (lo + hi) >> 1; if (batch[mid] < g) lo = mid + 1; else hi = mid; }
    const int start = lo;
    hi = n;
    while (lo < hi) { int mid = (lo + hi) >> 1; if (batch[mid] < g + 1) lo = mid + 1; else hi = mid; }
    const int end = lo;

    float s = 0.f;
    for (int v = start + w; v < end; v += 4)
        s += out2[(size_t)v * 64 + lane];
    red[w][lane] = s;
    __syncthreads();
    if (w == 0) {
        float tot = red[0][lane] + red[1][lane] + red[2][lane] + red[3][lane];
        float cnt = fmaxf((float)(end - start), 1.0f);
        hg_s[lane] = tot / cnt;
    }
    __syncthreads();
    if (t < 32) {
        float a = fc1b[t];
        #pragma unroll
        for (int k = 0; k < 64; ++k) a = fmaf(hg_s[k], fc1w[k * 32 + t], a);
        x1_s[t] = fmaxf(a, 0.f);
    }
    __syncthreads();
    if (t < 16) {
        float a = fc2b[t];
        #pragma unroll
        for (int k = 0; k < 32; ++k) a = fmaf(x1_s[k], fc2w[k * 16 + t], a);
        x2_s[t] = fmaxf(a, 0.f);
    }
    __syncthreads();
    if (t < DOUT) {
        float a = fcb[t];
        #pragma unroll
        for (int k = 0; k < 16; ++k) a = fmaf(x2_s[k], fcw[k * 10 + t], a);
        outc[g * DOUT + t] = a;
    }
    if (t < 16) outx2[g * 16 + t] = x2_s[t];
}

// ---------------------------------------------------------------------------
extern "C" void kernel_launch(void* const* d_in, const int* in_sizes, int n_in,
                              void* d_out, int out_size, void* d_ws, size_t ws_size,
                              hipStream_t stream) {
    const float* x    = (const float*)d_in[0];
    const int*   ei   = (const int*)d_in[1];
    const int*   batch= (const int*)d_in[2];
    const float* W1l  = (const float*)d_in[3];
    const float* W1r  = (const float*)d_in[4];
    const float* a1   = (const float*)d_in[5];
    const float* b1   = (const float*)d_in[6];
    const float* W2l  = (const float*)d_in[7];
    const float* W2r  = (const float*)d_in[8];
    const float* a2   = (const float*)d_in[9];
    const float* b2   = (const float*)d_in[10];
    const float* fc1w = (const float*)d_in[11];
    const float* fc1b = (const float*)d_in[12];
    const float* fc2w = (const float*)d_in[13];
    const float* fc2b = (const float*)d_in[14];
    const float* fcw  = (const float*)d_in[15];
    const float* fcb  = (const float*)d_in[16];

    const int N = in_sizes[2];          // 30000
    const int E = in_sizes[1] / 2;      // 480000
    const int ET = E + N;
    const int* esrc = ei;
    const int* edst = ei + E;
    const int NB = (N + SCAN_B - 1) / SCAN_B;   // 59 (<=64)

    // workspace layout
    char* ws = (char*)d_ws;
    size_t off = 0;
    unsigned short* xlr1b = (unsigned short*)(ws + off); off += (size_t)N * 512 * 2;  // [N,512] xl|xr bf16
    unsigned short* h1b  = (unsigned short*)(ws + off);  off += (size_t)N * 256 * 2;  // packed [N/16][8][64][8]
    float* out2 = (float*)(ws + off);            off += (size_t)N * 64 * 4;           // [N,64] f32
    int*   deg   = (int*)(ws + off);             off += ((size_t)(N + 1) * 4 + 255) & ~255ull;
    int*   cursor= (int*)(ws + off);             off += ((size_t)N * 4 + 255) & ~255ull;
    int*   csr   = (int*)(ws + off);             off += ((size_t)ET * 4 + 255) & ~255ull;
    int*   bsum  = (int*)(ws + off);             off += ((size_t)(NB + 1) * 4 + 255) & ~255ull;
    short* B1th  = (short*)(ws + off);           off += (size_t)512 * 128 * 2;        // packed
    short* B1tl  = (short*)(ws + off);           off += (size_t)512 * 128 * 2;        // packed
    short* B2th  = (short*)(ws + off);           off += (size_t)128 * 256 * 2;        // packed
    short* B2tl  = (short*)(ws + off);           off += (size_t)128 * 256 * 2;        // packed
    unsigned short* xgh = (unsigned short*)(ws + off); off += (size_t)N * 128 * 2;    // packed hi
    unsigned short* xgl = (unsigned short*)(ws + off); off += (size_t)N * 128 * 2;    // packed lo
    unsigned short* xlr2b = xlr1b;               // [N,128] bf16 (reuse)
    (void)ws_size; (void)n_in; (void)out_size;

    float* outc  = (float*)d_out;
    float* outx2 = (float*)d_out + GNUM * DOUT;

    // Prep: zero deg + split x to packed bf16 hi/lo + split weights packed
    const int prep_tot = N * 32 + 512 * 128 + 128 * 256;
    k_prep<<<(prep_tot + 255) / 256, 256, 0, stream>>>(
        x, W1l, W1r, W2l, W2r, xgh, xgl, B1th, B1tl, B2th, B2tl, deg, N + 1, N);

    // CSR build
    int tb = 256;
    int gb = (ET + tb - 1) / tb;
    k_deg<<<gb, tb, 0, stream>>>(edst, deg, E, N);
    k_scan_partial<<<NB, SCAN_B, 0, stream>>>(deg, bsum, N);
    k_scan_apply<<<NB, SCAN_B, 0, stream>>>(deg, cursor, bsum, N, NB);
    k_scatter<<<gb, tb, 0, stream>>>(esrc, edst, cursor, csr, E, N);

    // Layer 1 GEMM (packed fragments): xlr1b[N,512]
    dim3 g1((N + 127) / 128, 4);
    k_gemm1<<<g1, 256, 0, stream>>>(xgh, xgl, B1th, B1tl, xlr1b, N, 512);

    // Layer 1 edge pass -> h1b (packed for gemm_bf)
    k_edge1<<<N, 64, 0, stream>>>(xlr1b, deg, csr, a1, b1, h1b, N);

    // Layer 2 GEMM (packed fragments, 128x64 tiles): xlr2b[N,128]
    dim3 g2((N + 127) / 128, 2);
    k_gemm_bf<<<g2, 256, 0, stream>>>(h1b, B2th, B2tl, xlr2b, N, 128);

    // Layer 2 edge pass -> out2 (f32)
    k_edge2<<<N, 64, 0, stream>>>(xlr2b, deg, csr, a2, b2, out2, N);

    // Fused pool + MLP
    k_pool_mlp<<<GNUM, 256, 0, stream>>>(out2, batch, fc1w, fc1b, fc2w, fc2b,
                                         fcw, fcb, outc, outx2, N);
}

// Round 3
// 275.231 us; speedup vs baseline: 1.0749x; 1.0254x over previous
//
#include <hip/hip_runtime.h>
#include <math.h>

#define DIN 128
#define DH  32
#define H1  8
#define H2  2
#define GNUM 64
#define DOUT 10
#define NEG_SLOPE 0.2f
#define SCAN_B 512

typedef __attribute__((ext_vector_type(8))) short sv8;
typedef __attribute__((ext_vector_type(4))) float fv4;

static __device__ __forceinline__ unsigned short f2bf(float f) {
    unsigned int u = __float_as_uint(f);
    unsigned int r = (u + 0x7fffu + ((u >> 16) & 1u)) >> 16;
    return (unsigned short)r;
}
static __device__ __forceinline__ float bf2f(unsigned short h) {
    return __uint_as_float(((unsigned int)h) << 16);
}

// Packed fragment layout for MFMA operands:
//   element (row, k) lives at ((row/16 * NC + k/32) * 64 + ((k>>3)&3)*16 + (row&15)) * 8 + (k&7)
// where NC = K/32. A wave's fragment load for (rowgroup R, kchunk c) is then
//   base + ((R*NC + c)*64 + lane)*8   -- lane-contiguous 16B => fully coalesced.

// ---------------------------------------------------------------------------
// Prep: zero deg, split x -> bf16 hi|lo PACKED, transpose+split W1/W2 PACKED
// ---------------------------------------------------------------------------
__global__ void k_prep(const float* __restrict__ x,
                       const float* __restrict__ W1l, const float* __restrict__ W1r,
                       const float* __restrict__ W2l, const float* __restrict__ W2r,
                       unsigned short* __restrict__ xgh, unsigned short* __restrict__ xgl,
                       short* __restrict__ B1th, short* __restrict__ B1tl,
                       short* __restrict__ B2th, short* __restrict__ B2tl,
                       int* __restrict__ zbase, int nz, int n) {
    int id = blockIdx.x * blockDim.x + threadIdx.x;
    if (id < nz) zbase[id] = 0;        // deg[N+1]
    const int NX = n * 32;             // 32 threads per row of x
    const int T1 = 512 * 128;
    const int T2 = 128 * 256;
    if (id < NX) {
        int m = id >> 5, j4 = id & 31;           // k = j4*4
        float4 v = *(const float4*)(x + (size_t)m * 128 + j4 * 4);
        unsigned short hx = f2bf(v.x), hy = f2bf(v.y), hz = f2bf(v.z), hw = f2bf(v.w);
        ushort4 hi; hi.x = hx; hi.y = hy; hi.z = hz; hi.w = hw;
        ushort4 lo;
        lo.x = f2bf(v.x - bf2f(hx)); lo.y = f2bf(v.y - bf2f(hy));
        lo.z = f2bf(v.z - bf2f(hz)); lo.w = f2bf(v.w - bf2f(hw));
        int R = m >> 4, r = m & 15;
        int C = j4 >> 3, q = (j4 >> 1) & 3, j = (j4 & 1) * 4;
        size_t o = ((size_t)(R * 4 + C) * 64 + q * 16 + r) * 8 + j;
        *(ushort4*)(xgh + o) = hi;
        *(ushort4*)(xgl + o) = lo;
    } else if (id < NX + T1) {
        int id1 = id - NX;
        int nn = id1 / 128, k = id1 - nn * 128;   // nn: out-channel (512), k: K (128)
        float v = (nn < 256) ? W1l[(size_t)k * 256 + nn] : W1r[(size_t)k * 256 + (nn - 256)];
        unsigned short h = f2bf(v);
        size_t o = (((size_t)(nn >> 4) * 4 + (k >> 5)) * 64 + ((k >> 3) & 3) * 16 + (nn & 15)) * 8 + (k & 7);
        B1th[o] = (short)h;
        B1tl[o] = (short)f2bf(v - bf2f(h));
    } else if (id < NX + T1 + T2) {
        int id2 = id - NX - T1;
        int nn = id2 / 256, k = id2 - nn * 256;   // nn: out-channel (128), k: K (256)
        float v = (nn < 64) ? W2l[(size_t)k * 64 + nn] : W2r[(size_t)k * 64 + (nn - 64)];
        unsigned short h = f2bf(v);
        size_t o = (((size_t)(nn >> 4) * 8 + (k >> 5)) * 64 + ((k >> 3) & 3) * 16 + (nn & 15)) * 8 + (k & 7);
        B2th[o] = (short)h;
        B2tl[o] = (short)f2bf(v - bf2f(h));
    }
}

// ---------------------------------------------------------------------------
// CSR build
// ---------------------------------------------------------------------------
__global__ void k_deg(const int* __restrict__ dst, int* __restrict__ deg, int E, int n) {
    int i = blockIdx.x * blockDim.x + threadIdx.x;
    if (i < E) {
        atomicAdd(&deg[dst[i]], 1);
    } else if (i < E + n) {
        atomicAdd(&deg[i - E], 1);   // self loop
    }
}

__global__ __launch_bounds__(SCAN_B)
void k_scan_partial(const int* __restrict__ deg, int* __restrict__ bsum, int n) {
    int i = blockIdx.x * SCAN_B + threadIdx.x;
    int v = (i < n) ? deg[i] : 0;
    #pragma unroll
    for (int m = 32; m >= 1; m >>= 1) v += __shfl_xor(v, m);
    __shared__ int red[SCAN_B / 64];
    if ((threadIdx.x & 63) == 0) red[threadIdx.x >> 6] = v;
    __syncthreads();
    if (threadIdx.x == 0) {
        int s = 0;
        #pragma unroll
        for (int k = 0; k < SCAN_B / 64; ++k) s += red[k];
        bsum[blockIdx.x] = s;
    }
}

__global__ __launch_bounds__(SCAN_B)
void k_scan_apply(int* __restrict__ deg, int* __restrict__ cursor,
                  const int* __restrict__ bsum, int n, int nb) {
    __shared__ int buf[SCAN_B];
    __shared__ int pfx_s, tot_s;
    const int t = threadIdx.x, b = blockIdx.x;
    if (t < 64) {
        int v = (t < nb) ? bsum[t] : 0;
        int incl = v;
        #pragma unroll
        for (int o = 1; o < 64; o <<= 1) {
            int w = __shfl_up(incl, o);
            if (t >= o) incl += w;
        }
        int pfx = (b == 0) ? 0 : __shfl(incl, b - 1);
        int tot = __shfl(incl, nb - 1);
        if (t == 0) { pfx_s = pfx; tot_s = tot; }
    }
    int i = b * SCAN_B + t;
    int v = (i < n) ? deg[i] : 0;
    buf[t] = v;
    __syncthreads();
    for (int o = 1; o < SCAN_B; o <<= 1) {
        int a = (t >= o) ? buf[t - o] : 0;
        __syncthreads();
        buf[t] += a;
        __syncthreads();
    }
    int excl = buf[t] - v + pfx_s;
    if (i < n) { deg[i] = excl; cursor[i] = excl; }
    if (b == 0 && t == 0) deg[n] = tot_s;
}

__global__ void k_scatter(const int* __restrict__ src, const int* __restrict__ dst,
                          int* __restrict__ cursor, int* __restrict__ csr_src, int E, int n) {
    int i = blockIdx.x * blockDim.x + threadIdx.x;
    if (i < E) {
        int d = dst[i];
        int pos = atomicAdd(&cursor[d], 1);
        csr_src[pos] = src[i];
    } else if (i < E + n) {
        int v = i - E;
        int pos = atomicAdd(&cursor[v], 1);
        csr_src[pos] = v;   // self loop
    }
}

// ---------------------------------------------------------------------------
// Layer-1 GEMM: packed-fragment operands, fully coalesced lane-contiguous
// loads, zero K-loop barriers, zero LDS in main loop.
// A: xgh/xgl packed [M/16][4][64][8]; B: B1th/B1tl packed [32][4][64][8].
// 3 products: Ah*Bh + Ah*Bl + Al*Bh.
// ---------------------------------------------------------------------------
__global__ __launch_bounds__(256, 2)
void k_gemm1(const unsigned short* __restrict__ Ah, const unsigned short* __restrict__ Al,
             const short* __restrict__ Bth, const short* __restrict__ Btl,
             unsigned short* __restrict__ C,
             int M, int Ntot) {
    __shared__ float smc[64 * 68];
    const int tid = threadIdx.x;
    const int lane = tid & 63;
    const int wid = tid >> 6;
    const int wm = wid & 1, wn = wid >> 1;
    const int m0 = blockIdx.x * 128;
    const int n0 = blockIdx.y * 128;
    const int l15 = lane & 15, q = lane >> 4;
    const int MR = (M >> 4) - 1;

    fv4 acc[4][4] = {};

    const unsigned short* ap[4];
    const unsigned short* alp[4];
    #pragma unroll
    for (int fm = 0; fm < 4; ++fm) {
        int R = (m0 >> 4) + wm * 4 + fm;
        if (R > MR) R = MR;                      // tail clamp; stores guarded
        ap[fm]  = Ah + ((size_t)R * 4 * 64 + lane) * 8;
        alp[fm] = Al + ((size_t)R * 4 * 64 + lane) * 8;
    }
    const short* bhp[4];
    const short* blp[4];
    #pragma unroll
    for (int fn = 0; fn < 4; ++fn) {
        int R = (n0 >> 4) + wn * 4 + fn;
        bhp[fn] = Bth + ((size_t)R * 4 * 64 + lane) * 8;
        blp[fn] = Btl + ((size_t)R * 4 * 64 + lane) * 8;
    }

    #pragma unroll
    for (int c = 0; c < 4; ++c) {
        const size_t co = (size_t)c * 512;       // 64 lanes * 8 elems
        sv8 ah[4], al[4], bh[4], bl[4];
        #pragma unroll
        for (int fn = 0; fn < 4; ++fn) {
            bh[fn] = *(const sv8*)(bhp[fn] + co);
            bl[fn] = *(const sv8*)(blp[fn] + co);
        }
        #pragma unroll
        for (int fm = 0; fm < 4; ++fm) {
            ah[fm] = *(const sv8*)(ap[fm] + co);
            al[fm] = *(const sv8*)(alp[fm] + co);
        }
        #pragma unroll
        for (int fm = 0; fm < 4; ++fm) {
            #pragma unroll
            for (int fn = 0; fn < 4; ++fn) {
                acc[fm][fn] = __builtin_amdgcn_mfma_f32_16x16x32_bf16(ah[fm], bh[fn], acc[fm][fn], 0, 0, 0);
                acc[fm][fn] = __builtin_amdgcn_mfma_f32_16x16x32_bf16(ah[fm], bl[fn], acc[fm][fn], 0, 0, 0);
                acc[fm][fn] = __builtin_amdgcn_mfma_f32_16x16x32_bf16(al[fm], bh[fn], acc[fm][fn], 0, 0, 0);
            }
        }
    }

    // epilogue: 4 slices (row-half s x col-half cn), 64x64 each, bf16 only
    #pragma unroll
    for (int s = 0; s < 2; ++s) {
        #pragma unroll
        for (int cn = 0; cn < 2; ++cn) {
            __syncthreads();
            if (wm == s && wn == cn) {
                #pragma unroll
                for (int fm = 0; fm < 4; ++fm)
                    #pragma unroll
                    for (int fn = 0; fn < 4; ++fn)
                        #pragma unroll
                        for (int r = 0; r < 4; ++r)
                            smc[(fm * 16 + q * 4 + r) * 68 + fn * 16 + l15] = acc[fm][fn][r];
            }
            __syncthreads();
            int lr = tid >> 2;              // 0..63
            int grow = m0 + s * 64 + lr;
            if (grow < M) {
                #pragma unroll
                for (int k4 = 0; k4 < 4; ++k4) {
                    int jj = (tid & 3) + k4 * 4;    // 0..15 float4 index
                    float4 vv = *(float4*)&smc[lr * 68 + jj * 4];
                    int gcol = n0 + cn * 64 + jj * 4;
                    ushort4 uu;
                    uu.x = f2bf(vv.x); uu.y = f2bf(vv.y);
                    uu.z = f2bf(vv.z); uu.w = f2bf(vv.w);
                    *(ushort4*)(C + (size_t)grow * Ntot + gcol) = uu;
                }
            }
        }
    }
}

// ---------------------------------------------------------------------------
// Layer-2 GEMM: packed-fragment operands, K=256 (NC=8), tile 128x64.
// A: h1b packed [M/16][8][64][8]; B: B2th/B2tl packed [8][8][64][8].
// ---------------------------------------------------------------------------
__global__ __launch_bounds__(256, 2)
void k_gemm_bf(const unsigned short* __restrict__ A, const short* __restrict__ Bth,
               const short* __restrict__ Btl,
               unsigned short* __restrict__ C,
               int M, int Ntot) {
    __shared__ float smc[64 * 36];
    const int tid = threadIdx.x;
    const int lane = tid & 63;
    const int wid = tid >> 6;
    const int wm = wid & 1, wn = wid >> 1;   // wn in {0,1}: 32-col halves
    const int m0 = blockIdx.x * 128;
    const int n0 = blockIdx.y * 64;
    const int l15 = lane & 15, q = lane >> 4;
    const int MR = (M >> 4) - 1;

    fv4 acc[4][2] = {};

    const unsigned short* ap[4];
    #pragma unroll
    for (int fm = 0; fm < 4; ++fm) {
        int R = (m0 >> 4) + wm * 4 + fm;
        if (R > MR) R = MR;
        ap[fm] = A + ((size_t)R * 8 * 64 + lane) * 8;
    }
    const short* bhp[2];
    const short* blp[2];
    #pragma unroll
    for (int fn = 0; fn < 2; ++fn) {
        int R = (n0 >> 4) + wn * 2 + fn;
        bhp[fn] = Bth + ((size_t)R * 8 * 64 + lane) * 8;
        blp[fn] = Btl + ((size_t)R * 8 * 64 + lane) * 8;
    }

    #pragma unroll 4
    for (int c = 0; c < 8; ++c) {
        const size_t co = (size_t)c * 512;
        sv8 ah[4], bh[2], bl[2];
        #pragma unroll
        for (int fn = 0; fn < 2; ++fn) {
            bh[fn] = *(const sv8*)(bhp[fn] + co);
            bl[fn] = *(const sv8*)(blp[fn] + co);
        }
        #pragma unroll
        for (int fm = 0; fm < 4; ++fm)
            ah[fm] = *(const sv8*)(ap[fm] + co);
        #pragma unroll
        for (int fm = 0; fm < 4; ++fm) {
            #pragma unroll
            for (int fn = 0; fn < 2; ++fn) {
                acc[fm][fn] = __builtin_amdgcn_mfma_f32_16x16x32_bf16(ah[fm], bh[fn], acc[fm][fn], 0, 0, 0);
                acc[fm][fn] = __builtin_amdgcn_mfma_f32_16x16x32_bf16(ah[fm], bl[fn], acc[fm][fn], 0, 0, 0);
            }
        }
    }

    // epilogue: 4 slices (row-half s x col-half cn), 64x32 each
    #pragma unroll
    for (int s = 0; s < 2; ++s) {
        #pragma unroll
        for (int cn = 0; cn < 2; ++cn) {
            __syncthreads();
            if (wm == s && wn == cn) {
                #pragma unroll
                for (int fm = 0; fm < 4; ++fm)
                    #pragma unroll
                    for (int fn = 0; fn < 2; ++fn)
                        #pragma unroll
                        for (int r = 0; r < 4; ++r)
                            smc[(fm * 16 + q * 4 + r) * 36 + fn * 16 + l15] = acc[fm][fn][r];
            }
            __syncthreads();
            int lr = tid >> 2;              // 0..63
            int grow = m0 + s * 64 + lr;
            if (grow < M) {
                #pragma unroll
                for (int k4 = 0; k4 < 2; ++k4) {
                    int jj = (tid & 3) + k4 * 4;    // 0..7 float4 index
                    float4 vv = *(float4*)&smc[lr * 36 + jj * 4];
                    int gcol = n0 + cn * 32 + jj * 4;
                    ushort4 uu;
                    uu.x = f2bf(vv.x); uu.y = f2bf(vv.y);
                    uu.z = f2bf(vv.z); uu.w = f2bf(vv.w);
                    *(ushort4*)(C + (size_t)grow * Ntot + gcol) = uu;
                }
            }
        }
    }
}

// ---------------------------------------------------------------------------
// Layer-1 edge pass: 4 nodes per 256-thread block (one wave per node).
// XLR[N,512] bf16: cols 0..255 = xl, 256..511 = xr. lane li (0..31) owns
// 8 ch; half = edge slot. One-step software pipeline on the edge gather.
// Output h1b written in PACKED fragment layout for gemm_bf.
// ---------------------------------------------------------------------------
__global__ __launch_bounds__(256)
void k_edge1(const unsigned short* __restrict__ XLR,
             const int* __restrict__ offs, const int* __restrict__ csr,
             const float* __restrict__ att, const float* __restrict__ bias,
             unsigned short* __restrict__ out, int n) {
    const int tid = threadIdx.x;
    const int lane = tid & 63;
    const int v = blockIdx.x * 4 + (tid >> 6);
    if (v >= n) return;
    const int li = lane & 31;
    const int half = lane >> 5;
    const uint4* XL4 = (const uint4*)XLR;   // row = 64 uint4 (512 bf16)
    float av[8], xr[8];
    #pragma unroll
    for (int k = 0; k < 8; ++k) av[k] = att[li * 8 + k];
    {
        uint4 u = XL4[(size_t)v * 64 + 32 + li];
        xr[0] = __uint_as_float(u.x << 16);  xr[1] = __uint_as_float(u.x & 0xffff0000u);
        xr[2] = __uint_as_float(u.y << 16);  xr[3] = __uint_as_float(u.y & 0xffff0000u);
        xr[4] = __uint_as_float(u.z << 16);  xr[5] = __uint_as_float(u.z & 0xffff0000u);
        xr[6] = __uint_as_float(u.w << 16);  xr[7] = __uint_as_float(u.w & 0xffff0000u);
    }
    float z = 0.f;
    float acc[8] = {};
    const int e0 = offs[v], e1 = offs[v + 1];

    // software pipeline: this half-wave owns edges e0+half, e0+half+2, ...
    int j = e0 + half;
    bool val = (j < e1);
    int jj = val ? j : (e1 - 1);
    int src = csr[jj];
    uint4 u = XL4[(size_t)src * 64 + li];

    for (int base = e0; base < e1; base += 2) {
        // prefetch next pair
        int jn = j + 2;
        bool valn = (jn < e1);
        int jjn = valn ? jn : (e1 - 1);
        int srcn = csr[jjn];
        uint4 un = XL4[(size_t)srcn * 64 + li];

        // compute on current
        float f[8];
        f[0] = __uint_as_float(u.x << 16);  f[1] = __uint_as_float(u.x & 0xffff0000u);
        f[2] = __uint_as_float(u.y << 16);  f[3] = __uint_as_float(u.y & 0xffff0000u);
        f[4] = __uint_as_float(u.z << 16);  f[5] = __uint_as_float(u.z & 0xffff0000u);
        f[6] = __uint_as_float(u.w << 16);  f[7] = __uint_as_float(u.w & 0xffff0000u);
        float s1 = 0.f, s2 = 0.f;
        #pragma unroll
        for (int k = 0; k < 8; ++k) {
            float t = f[k] + xr[k];
            s1 = fmaf(t, av[k], s1);
            s2 = fmaf(fabsf(t), av[k], s2);
        }
        float s = fmaf(0.6f, s1, 0.4f * s2);
        s += __shfl_xor(s, 1);
        s += __shfl_xor(s, 2);
        float w = val ? __expf(s) : 0.f;
        z += w;
        #pragma unroll
        for (int k = 0; k < 8; ++k) acc[k] = fmaf(w, f[k], acc[k]);

        u = un; val = valn; j = jn;
    }
    z += __shfl_xor(z, 32);
    #pragma unroll
    for (int k = 0; k < 8; ++k) acc[k] += __shfl_xor(acc[k], 32);
    if (half == 0) {
        const float rz = 1.f / z;
        unsigned int o[4];
        #pragma unroll
        for (int k2 = 0; k2 < 4; ++k2) {
            float lo = fmaf(acc[k2 * 2 + 0], rz, bias[li * 8 + k2 * 2 + 0]);
            float hi = fmaf(acc[k2 * 2 + 1], rz, bias[li * 8 + k2 * 2 + 1]);
            lo = (lo > 0.f) ? lo : (__expf(lo) - 1.f);
            hi = (hi > 0.f) ? hi : (__expf(hi) - 1.f);
            o[k2] = (unsigned int)f2bf(lo) | ((unsigned int)f2bf(hi) << 16);
        }
        uint4 ov = { o[0], o[1], o[2], o[3] };
        // packed fragment layout: R=v>>4, C=li>>2, lane=(li&3)*16+(v&15)
        size_t po = (((size_t)(v >> 4) * 8 + (li >> 2)) * 64 + (li & 3) * 16 + (v & 15)) * 8;
        *(uint4*)(out + po) = ov;
    }
}

// ---------------------------------------------------------------------------
// Layer-2 edge pass: 4 nodes per 256-thread block (one wave per node).
// XLR[N,128] bf16: cols 0..63 = xl, 64..127 = xr. lane li (0..7) owns 8 ch;
// slot = lane>>3 (8 edge slots). One-step software pipeline.
// ---------------------------------------------------------------------------
__global__ __launch_bounds__(256)
void k_edge2(const unsigned short* __restrict__ XLR,
             const int* __restrict__ offs, const int* __restrict__ csr,
             const float* __restrict__ att, const float* __restrict__ bias,
             float* __restrict__ out, int n) {
    const int tid = threadIdx.x;
    const int lane = tid & 63;
    const int v = blockIdx.x * 4 + (tid >> 6);
    if (v >= n) return;
    const int li = lane & 7;
    const int slot = lane >> 3;
    const uint4* XL4 = (const uint4*)XLR;   // row = 16 uint4 (128 bf16)
    float av[8], xr[8];
    #pragma unroll
    for (int k = 0; k < 8; ++k) av[k] = att[li * 8 + k];
    {
        uint4 u = XL4[(size_t)v * 16 + 8 + li];
        xr[0] = __uint_as_float(u.x << 16);  xr[1] = __uint_as_float(u.x & 0xffff0000u);
        xr[2] = __uint_as_float(u.y << 16);  xr[3] = __uint_as_float(u.y & 0xffff0000u);
        xr[4] = __uint_as_float(u.z << 16);  xr[5] = __uint_as_float(u.z & 0xffff0000u);
        xr[6] = __uint_as_float(u.w << 16);  xr[7] = __uint_as_float(u.w & 0xffff0000u);
    }
    float z = 0.f;
    float acc[8] = {};
    const int e0 = offs[v], e1 = offs[v + 1];

    int j = e0 + slot;
    bool val = (j < e1);
    int jj = val ? j : (e1 - 1);
    int src = csr[jj];
    uint4 u = XL4[(size_t)src * 16 + li];

    for (int base = e0; base < e1; base += 8) {
        int jn = j + 8;
        bool valn = (jn < e1);
        int jjn = valn ? jn : (e1 - 1);
        int srcn = csr[jjn];
        uint4 un = XL4[(size_t)srcn * 16 + li];

        float f[8];
        f[0] = __uint_as_float(u.x << 16);  f[1] = __uint_as_float(u.x & 0xffff0000u);
        f[2] = __uint_as_float(u.y << 16);  f[3] = __uint_as_float(u.y & 0xffff0000u);
        f[4] = __uint_as_float(u.z << 16);  f[5] = __uint_as_float(u.z & 0xffff0000u);
        f[6] = __uint_as_float(u.w << 16);  f[7] = __uint_as_float(u.w & 0xffff0000u);
        float s1 = 0.f, s2 = 0.f;
        #pragma unroll
        for (int k = 0; k < 8; ++k) {
            float t = f[k] + xr[k];
            s1 = fmaf(t, av[k], s1);
            s2 = fmaf(fabsf(t), av[k], s2);
        }
        float s = fmaf(0.6f, s1, 0.4f * s2);
        s += __shfl_xor(s, 1);
        s += __shfl_xor(s, 2);
        float w = val ? __expf(s) : 0.f;
        z += w;
        #pragma unroll
        for (int k = 0; k < 8; ++k) acc[k] = fmaf(w, f[k], acc[k]);

        u = un; val = valn; j = jn;
    }
    z += __shfl_xor(z, 8);  z += __shfl_xor(z, 16);  z += __shfl_xor(z, 32);
    #pragma unroll
    for (int k = 0; k < 8; ++k) {
        acc[k] += __shfl_xor(acc[k], 8);
        acc[k] += __shfl_xor(acc[k], 16);
        acc[k] += __shfl_xor(acc[k], 32);
    }
    if (slot == 0) {
        const float rz = 1.f / z;
        float o[8];
        #pragma unroll
        for (int k = 0; k < 8; ++k)
            o[k] = fmaf(acc[k], rz, bias[li * 8 + k]);
        float4 o0 = { o[0], o[1], o[2], o[3] };
        float4 o1 = { o[4], o[5], o[6], o[7] };
        *(float4*)(out + (size_t)v * 64 + li * 8 + 0) = o0;
        *(float4*)(out + (size_t)v * 64 + li * 8 + 4) = o1;
    }
}

// ---------------------------------------------------------------------------
// Fused mean-pool + MLP head: one block per graph.
// ---------------------------------------------------------------------------
__global__ __launch_bounds__(256)
void k_pool_mlp(const float* __restrict__ out2, const int* __restrict__ batch,
                const float* __restrict__ fc1w, const float* __restrict__ fc1b,
                const float* __restrict__ fc2w, const float* __restrict__ fc2b,
                const float* __restrict__ fcw,  const float* __restrict__ fcb,
                float* __restrict__ outc, float* __restrict__ outx2, int n) {
    const int g = blockIdx.x;
    const int t = threadIdx.x;
    const int lane = t & 63;
    const int w = t >> 6;
    __shared__ float red[4][64];
    __shared__ float hg_s[64];
    __shared__ float x1_s[32];
    __shared__ float x2_s[16];

    int lo = 0, hi = n;
    while (lo < hi) { int mid = (lo + hi) >> 1; if (batch[mid] < g) lo = mid + 1; else hi = mid; }
    const int start = lo;
    hi = n;
    while (lo < hi) { int mid = (lo + hi) >> 1; if (batch[mid] < g + 1) lo = mid + 1; else hi = mid; }
    const int end = lo;

    float s = 0.f;
    for (int v = start + w; v < end; v += 4)
        s += out2[(size_t)v * 64 + lane];
    red[w][lane] = s;
    __syncthreads();
    if (w == 0) {
        float tot = red[0][lane] + red[1][lane] + red[2][lane] + red[3][lane];
        float cnt = fmaxf((float)(end - start), 1.0f);
        hg_s[lane] = tot / cnt;
    }
    __syncthreads();
    if (t < 32) {
        float a = fc1b[t];
        #pragma unroll
        for (int k = 0; k < 64; ++k) a = fmaf(hg_s[k], fc1w[k * 32 + t], a);
        x1_s[t] = fmaxf(a, 0.f);
    }
    __syncthreads();
    if (t < 16) {
        float a = fc2b[t];
        #pragma unroll
        for (int k = 0; k < 32; ++k) a = fmaf(x1_s[k], fc2w[k * 16 + t], a);
        x2_s[t] = fmaxf(a, 0.f);
    }
    __syncthreads();
    if (t < DOUT) {
        float a = fcb[t];
        #pragma unroll
        for (int k = 0; k < 16; ++k) a = fmaf(x2_s[k], fcw[k * 10 + t], a);
        outc[g * DOUT + t] = a;
    }
    if (t < 16) outx2[g * 16 + t] = x2_s[t];
}

// ---------------------------------------------------------------------------
extern "C" void kernel_launch(void* const* d_in, const int* in_sizes, int n_in,
                              void* d_out, int out_size, void* d_ws, size_t ws_size,
                              hipStream_t stream) {
    const float* x    = (const float*)d_in[0];
    const int*   ei   = (const int*)d_in[1];
    const int*   batch= (const int*)d_in[2];
    const float* W1l  = (const float*)d_in[3];
    const float* W1r  = (const float*)d_in[4];
    const float* a1   = (const float*)d_in[5];
    const float* b1   = (const float*)d_in[6];
    const float* W2l  = (const float*)d_in[7];
    const float* W2r  = (const float*)d_in[8];
    const float* a2   = (const float*)d_in[9];
    const float* b2   = (const float*)d_in[10];
    const float* fc1w = (const float*)d_in[11];
    const float* fc1b = (const float*)d_in[12];
    const float* fc2w = (const float*)d_in[13];
    const float* fc2b = (const float*)d_in[14];
    const float* fcw  = (const float*)d_in[15];
    const float* fcb  = (const float*)d_in[16];

    const int N = in_sizes[2];          // 30000
    const int E = in_sizes[1] / 2;      // 480000
    const int ET = E + N;
    const int* esrc = ei;
    const int* edst = ei + E;
    const int NB = (N + SCAN_B - 1) / SCAN_B;   // 59 (<=64)

    // workspace layout
    char* ws = (char*)d_ws;
    size_t off = 0;
    unsigned short* xlr1b = (unsigned short*)(ws + off); off += (size_t)N * 512 * 2;  // [N,512] xl|xr bf16
    unsigned short* h1b  = (unsigned short*)(ws + off);  off += (size_t)N * 256 * 2;  // packed [N/16][8][64][8]
    float* out2 = (float*)(ws + off);            off += (size_t)N * 64 * 4;           // [N,64] f32
    int*   deg   = (int*)(ws + off);             off += ((size_t)(N + 1) * 4 + 255) & ~255ull;
    int*   cursor= (int*)(ws + off);             off += ((size_t)N * 4 + 255) & ~255ull;
    int*   csr   = (int*)(ws + off);             off += ((size_t)ET * 4 + 255) & ~255ull;
    int*   bsum  = (int*)(ws + off);             off += ((size_t)(NB + 1) * 4 + 255) & ~255ull;
    short* B1th  = (short*)(ws + off);           off += (size_t)512 * 128 * 2;        // packed
    short* B1tl  = (short*)(ws + off);           off += (size_t)512 * 128 * 2;        // packed
    short* B2th  = (short*)(ws + off);           off += (size_t)128 * 256 * 2;        // packed
    short* B2tl  = (short*)(ws + off);           off += (size_t)128 * 256 * 2;        // packed
    unsigned short* xgh = (unsigned short*)(ws + off); off += (size_t)N * 128 * 2;    // packed hi
    unsigned short* xgl = (unsigned short*)(ws + off); off += (size_t)N * 128 * 2;    // packed lo
    unsigned short* xlr2b = xlr1b;               // [N,128] bf16 (reuse)
    (void)ws_size; (void)n_in; (void)out_size;

    float* outc  = (float*)d_out;
    float* outx2 = (float*)d_out + GNUM * DOUT;

    // Prep: zero deg + split x to packed bf16 hi/lo + split weights packed
    const int prep_tot = N * 32 + 512 * 128 + 128 * 256;
    k_prep<<<(prep_tot + 255) / 256, 256, 0, stream>>>(
        x, W1l, W1r, W2l, W2r, xgh, xgl, B1th, B1tl, B2th, B2tl, deg, N + 1, N);

    // CSR build
    int tb = 256;
    int gb = (ET + tb - 1) / tb;
    k_deg<<<gb, tb, 0, stream>>>(edst, deg, E, N);
    k_scan_partial<<<NB, SCAN_B, 0, stream>>>(deg, bsum, N);
    k_scan_apply<<<NB, SCAN_B, 0, stream>>>(deg, cursor, bsum, N, NB);
    k_scatter<<<gb, tb, 0, stream>>>(esrc, edst, cursor, csr, E, N);

    // Layer 1 GEMM (packed fragments): xlr1b[N,512]
    dim3 g1((N + 127) / 128, 4);
    k_gemm1<<<g1, 256, 0, stream>>>(xgh, xgl, B1th, B1tl, xlr1b, N, 512);

    // Layer 1 edge pass -> h1b (packed for gemm_bf), 4 nodes/block
    k_edge1<<<(N + 3) / 4, 256, 0, stream>>>(xlr1b, deg, csr, a1, b1, h1b, N);

    // Layer 2 GEMM (packed fragments, 128x64 tiles): xlr2b[N,128]
    dim3 g2((N + 127) / 128, 2);
    k_gemm_bf<<<g2, 256, 0, stream>>>(h1b, B2th, B2tl, xlr2b, N, 128);

    // Layer 2 edge pass -> out2 (f32), 4 nodes/block
    k_edge2<<<(N + 3) / 4, 256, 0, stream>>>(xlr2b, deg, csr, a2, b2, out2, N);

    // Fused pool + MLP
    k_pool_mlp<<<GNUM, 256, 0, stream>>>(out2, batch, fc1w, fc1b, fc2w, fc2b,
                                         fcw, fcb, outc, outx2, N);
}